// Round 11
// baseline (126.007 us; speedup 1.0000x reference)
//
#include <hip/hip_runtime.h>
#include <stdint.h>

#define SS 2048
#define BB 16
#define DD 128
#define DVV 128
#define BQ 64                   // q-rows per block (4 qsub-waves x 16 rows)
#define BK 32
#define NTILES (SS / BK)        // 64 k-tiles per batch
#define TILE_HW 4096            // 8 KB tile image = 4096 halfwords

typedef __attribute__((ext_vector_type(8))) short short8;
typedef __attribute__((ext_vector_type(4))) float float4v;

typedef __attribute__((address_space(1))) const void glob_cv;
typedef __attribute__((address_space(3))) void lds_v;

// RTNE float -> bf16 (inputs finite)
__device__ __forceinline__ short f2bf(float f) {
  union { float f; uint32_t u; } x;
  x.f = f;
  uint32_t r = x.u + 0x7fffu + ((x.u >> 16) & 1u);
  return (short)(r >> 16);
}

// key permutation kappa: PV fragment slot (quad, j) <-> key (verified R4/R5)
__device__ __forceinline__ int kappa(int quad, int j) {
  return (j < 4) ? (quad * 4 + j) : (16 + quad * 4 + (j - 4));
}

// ---- preconvert K and V into FRAGMENT-LINEAR images (VERBATIM, verified) ----
__global__ __launch_bounds__(256) void conv_kv(
    const float* __restrict__ kg, const float* __restrict__ vg,
    short* __restrict__ kimg, short* __restrict__ vimg) {
  __shared__ short tile[BK][136];
  const int t = blockIdx.x, b = blockIdx.y;
  const float* src_base = (blockIdx.z == 0) ? kg : vg;
  short* out = ((blockIdx.z == 0) ? kimg : vimg) + ((size_t)(b * NTILES + t)) * TILE_HW;
#pragma unroll
  for (int p = 0; p < 2; ++p) {
    const int ch = threadIdx.x + p * 256;  // key*16 + c
    const int key = ch >> 4, c = ch & 15;
    const float* src = src_base + ((size_t)(t * BK + key) * BB + b) * DD + c * 8;
    float4v f0 = *(const float4v*)src;
    float4v f1 = *(const float4v*)(src + 4);
    short8 s;
#pragma unroll
    for (int i = 0; i < 4; ++i) { s[i] = f2bf(f0[i]); s[4 + i] = f2bf(f1[i]); }
    *(short8*)&tile[key][c * 8] = s;
  }
  __syncthreads();
#pragma unroll
  for (int p = 0; p < 2; ++p) {
    const int idx = threadIdx.x + p * 256;
    const int j = idx >> 6, quad = (idx >> 4) & 3, mm = idx & 15;
    short8 s;
    if (blockIdx.z == 0) {
      const int ks = j >> 1, half = j & 1;
      s = *(const short8*)&tile[half * 16 + mm][(ks * 4 + quad) * 8];
    } else {
#pragma unroll
      for (int jj = 0; jj < 8; ++jj) s[jj] = tile[kappa(quad, jj)][j * 16 + mm];
    }
    *(short8*)(out + idx * 8) = s;
  }
}

// ---- attention: R10 structure (verified), with the end-of-round
//      __syncthreads (implicit vmcnt(0) drain) replaced by T4 counted-vmcnt
//      + raw-barrier discipline: waits land on loads aged a FULL round. ----
__global__ __launch_bounds__(512) void attn_fwd(
    const float* __restrict__ qg, const short* __restrict__ kimg,
    const short* __restrict__ vimg, float* __restrict__ og) {
  // staging: 2 bufs x 2 parity groups x 8192 shorts (16 KB tile-pair) = 64 KB.
  // combine overlay (36,864 B) aliases the same region after the loop.
  __shared__ __align__(16) char smem_raw[65536];
  short* const sbuf = (short*)smem_raw;

  const int tid  = threadIdx.x;
  const int wave = tid >> 6;    // 0..7
  const int par  = wave >> 2;   // tile-stream parity of this wave's group
  const int qsub = wave & 3;    // q-row group: rows [qt*64 + qsub*16, +16)
  const int lane = tid & 63;
  const int m    = lane & 15;
  const int quad = lane >> 4;
  const int bid  = blockIdx.x;
  // XCD-local dispatch (verified R4-R10)
  const int xcd = bid & 7;
  const int j   = bid >> 3;                 // 0..63
  const int qt  = (j < 32) ? j : 63 - j;    // 0..31
  const int b   = 2 * xcd + (j >> 5);
  const int qw  = qt * BQ + qsub * 16;
  const int qrow = qw + m;

  // Q fragments (B operand: lane&15 = q-row), 1/sqrt(D)*log2(e) folded
  const float cscale = 0.08838834764831845f * 1.4426950408889634f;
  short8 qfrag[4];
#pragma unroll
  for (int ks = 0; ks < 4; ++ks) {
    const float* qp = qg + ((size_t)qrow * BB + b) * DD + ks * 32 + quad * 8;
    float4v f0 = *(const float4v*)qp;
    float4v f1 = *(const float4v*)(qp + 4);
    short8 f;
#pragma unroll
    for (int i = 0; i < 4; ++i) { f[i] = f2bf(f0[i] * cscale); f[4 + i] = f2bf(f1[i] * cscale); }
    qfrag[ks] = f;
  }

  // ones-fragment for the psum MFMA (verified R10)
  short8 vones;
#pragma unroll
  for (int i = 0; i < 8; ++i) vones[i] = (short)0x3F80;

  float4v oacc[8];
#pragma unroll
  for (int i = 0; i < 8; ++i) oacc[i] = (float4v){0.f, 0.f, 0.f, 0.f};
  float4v psacc = {0.f, 0.f, 0.f, 0.f};

  // staging (verified chunk math): K: LDS chunks 0..7, V: 8..15; wave qsub
  // owns chunks [4*qsub, 4*qsub+4). LDS dst wave-uniform; global src per-lane.
  const short* kbase = kimg + (size_t)b * NTILES * TILE_HW;
  const short* vbase = vimg + (size_t)b * NTILES * TILE_HW;
  const int cbase = qsub * 4;                       // 0,4,8,12
  const short* timg = (cbase < 8) ? kbase : vbase;  // qsub 0,1: K; 2,3: V
  const int coff = cbase & 7;                       // 0,4,0,4
  short* const gbuf0 = sbuf + par * 8192;           // buf 0
  short* const gbuf1 = sbuf + 16384 + par * 8192;   // buf 1

  const int nround = qt + 1;  // tiles t = 2r+par, t <= 2qt+1 always valid

  // prologue: issue round-0 tile (t = par) into buf 0 (4 loads, no wait here;
  // round 0's vmcnt+barrier publishes it)
  {
    const short* src = timg + (size_t)par * TILE_HW + coff * 512 + lane * 8;
#pragma unroll
    for (int c = 0; c < 4; ++c)
      __builtin_amdgcn_global_load_lds((glob_cv*)(src + c * 512),
                                       (lds_v*)&gbuf0[(cbase + c) * 512], 16, 0, 0);
  }

  for (int r = 0; r < nround; ++r) {
    short* const cbuf = (r & 1) ? gbuf1 : gbuf0;  // compute from this buffer
    short* const nbuf = (r & 1) ? gbuf0 : gbuf1;  // stage next tile here

    // A: issue prefetch(r+1); B: wait for tile-r's loads (aged a full round).
    // Block-uniform branch: last round has only tile-r's 4 loads outstanding.
    if (r + 1 < nround) {
      const int tn = 2 * (r + 1) + par;
      const short* src = timg + (size_t)tn * TILE_HW + coff * 512 + lane * 8;
#pragma unroll
      for (int c = 0; c < 4; ++c)
        __builtin_amdgcn_global_load_lds((glob_cv*)(src + c * 512),
                                         (lds_v*)&nbuf[(cbase + c) * 512], 16, 0, 0);
      asm volatile("s_waitcnt vmcnt(4)" ::: "memory");  // oldest 4 = tile r
    } else {
      asm volatile("s_waitcnt vmcnt(0)" ::: "memory");
    }
    __builtin_amdgcn_s_barrier();          // C: cbuf published to all waves
    __builtin_amdgcn_sched_barrier(0);     // rule #18: no hoisting across

    const int t = 2 * r + par;
    const short* kb = cbuf;
    const short* vb = cbuf + 8 * 512;

    // ---- S = K·Q^T (verbatim R10) ----
    float4v s0 = {0.f, 0.f, 0.f, 0.f}, s1 = {0.f, 0.f, 0.f, 0.f};
    __builtin_amdgcn_s_setprio(1);
#pragma unroll
    for (int ks = 0; ks < 4; ++ks) {
      short8 kf0 = *(const short8*)(kb + (ks * 2 + 0) * 512 + lane * 8);
      short8 kf1 = *(const short8*)(kb + (ks * 2 + 1) * 512 + lane * 8);
      s0 = __builtin_amdgcn_mfma_f32_16x16x32_bf16(kf0, qfrag[ks], s0, 0, 0, 0);
      s1 = __builtin_amdgcn_mfma_f32_16x16x32_bf16(kf1, qfrag[ks], s1, 0, 0, 0);
    }
    __builtin_amdgcn_s_setprio(0);
    float sv[8];
#pragma unroll
    for (int rr = 0; rr < 4; ++rr) { sv[rr] = s0[rr]; sv[4 + rr] = s1[rr]; }

    const int kt0 = t * BK;
    if (kt0 + BK - 1 > qw) {  // wave-uniform: diagonal/above tiles only
#pragma unroll
      for (int jj = 0; jj < 8; ++jj)
        if (kt0 + kappa(quad, jj) > qrow) sv[jj] = -1e30f;
    }

    // ---- fixed-reference softmax (verbatim R10) ----
    union { short8 s8; uint32_t w[4]; } pf;
#pragma unroll
    for (int jp = 0; jp < 4; ++jp) {
      float p0 = exp2f(sv[2 * jp]);
      float p1 = exp2f(sv[2 * jp + 1]);
      uint32_t w;
      asm("v_cvt_pk_bf16_f32 %0, %1, %2" : "=v"(w) : "v"(p0), "v"(p1));
      pf.w[jp] = w;
    }
    const short8 pfrag = pf.s8;

    // ---- psum MFMA + PV (verbatim R10) ----
    __builtin_amdgcn_s_setprio(1);
    psacc = __builtin_amdgcn_mfma_f32_16x16x32_bf16(pfrag, vones, psacc, 0, 0, 0);
#pragma unroll
    for (int nt = 0; nt < 8; ++nt) {
      short8 vf = *(const short8*)(vb + nt * 512 + lane * 8);
      oacc[nt] = __builtin_amdgcn_mfma_f32_16x16x32_bf16(pfrag, vf, oacc[nt], 0, 0, 0);
    }
    __builtin_amdgcn_s_setprio(0);

    // E/F: my cbuf ds_reads done (cheap: MFMAs consumed them) -> barrier ->
    // next round may overwrite cbuf. No vmcnt drain here (the T4 win).
    asm volatile("s_waitcnt lgkmcnt(0)" ::: "memory");
    __builtin_amdgcn_s_barrier();
    __builtin_amdgcn_sched_barrier(0);
  }

  // ---- combine parity-1 partials into parity-0 waves (verbatim R10) ----
  __syncthreads();  // full drain once; overlay smem as float scratch
  float* const cw = (float*)smem_raw;  // 256*36*4 = 36,864 B <= 65,536 B
  if (par == 1) {
    float* p = cw + (size_t)(qsub * 64 + lane) * 36;
#pragma unroll
    for (int nt = 0; nt < 8; ++nt) *(float4v*)(p + nt * 4) = oacc[nt];
    *(float4v*)(p + 32) = psacc;
  }
  __syncthreads();
  if (par == 0) {
    const float* p = cw + (size_t)(qsub * 64 + lane) * 36;
#pragma unroll
    for (int nt = 0; nt < 8; ++nt) oacc[nt] += *(const float4v*)(p + nt * 4);
    psacc += *(const float4v*)(p + 32);

    // ---- epilogue (verbatim R10): psacc[rr] = rowsum(qw + quad*4 + rr) ----
    float l4[4];
#pragma unroll
    for (int rr = 0; rr < 4; ++rr) l4[rr] = 1.0f / psacc[rr];
#pragma unroll
    for (int rr = 0; rr < 4; ++rr) {
      const int qgl = qw + quad * 4 + rr;
      float* op = og + ((size_t)qgl * BB + b) * DVV + m;
#pragma unroll
      for (int nt = 0; nt < 8; ++nt) op[nt * 16] = oacc[nt][rr] * l4[rr];
    }
  }
}

extern "C" void kernel_launch(void* const* d_in, const int* in_sizes, int n_in,
                              void* d_out, int out_size, void* d_ws, size_t ws_size,
                              hipStream_t stream) {
  const float* q = (const float*)d_in[0];
  const float* k = (const float*)d_in[1];
  const float* v = (const float*)d_in[2];
  float* out = (float*)d_out;
  short* kimg = (short*)d_ws;
  short* vimg = kimg + (size_t)BB * NTILES * TILE_HW;  // 8.39 MB each

  conv_kv<<<dim3(NTILES, BB, 2), 256, 0, stream>>>(k, v, kimg, vimg);
  attn_fwd<<<dim3(SS / BQ * BB), 512, 0, stream>>>(q, kimg, vimg, out);
}

// Round 12
// 122.339 us; speedup vs baseline: 1.0300x; 1.0300x over previous
//
#include <hip/hip_runtime.h>
#include <stdint.h>

#define SS 2048
#define BB 16
#define DD 128
#define DVV 128
#define BQ 64                   // q-rows per block (4 qsub-waves x 16 rows)
#define BK 32
#define NTILES (SS / BK)        // 64 k-tiles per batch
#define TILE_HW 4096            // 8 KB tile image = 4096 halfwords

typedef __attribute__((ext_vector_type(8))) short short8;
typedef __attribute__((ext_vector_type(4))) float float4v;

typedef __attribute__((address_space(1))) const void glob_cv;
typedef __attribute__((address_space(3))) void lds_v;

// RTNE float -> bf16 (inputs finite)
__device__ __forceinline__ short f2bf(float f) {
  union { float f; uint32_t u; } x;
  x.f = f;
  uint32_t r = x.u + 0x7fffu + ((x.u >> 16) & 1u);
  return (short)(r >> 16);
}

// key permutation kappa: PV fragment slot (quad, j) <-> key (verified R4/R5)
__device__ __forceinline__ int kappa(int quad, int j) {
  return (j < 4) ? (quad * 4 + j) : (16 + quad * 4 + (j - 4));
}

// ---- preconvert K and V into FRAGMENT-LINEAR images (VERBATIM, verified) ----
// chunk idx in [0,512): lane l = idx&63 reads 16B at tile_base + idx*16B in attn.
// K image: j = idx>>6 = ks*2+half; content K[half*16 + (l&15)][(ks*4 + (l>>4))*8 + i]
// V image: nt = idx>>6;            content V[kappa(l>>4, i)][nt*16 + (l&15)]
__global__ __launch_bounds__(256) void conv_kv(
    const float* __restrict__ kg, const float* __restrict__ vg,
    short* __restrict__ kimg, short* __restrict__ vimg) {
  __shared__ short tile[BK][136];
  const int t = blockIdx.x, b = blockIdx.y;
  const float* src_base = (blockIdx.z == 0) ? kg : vg;
  short* out = ((blockIdx.z == 0) ? kimg : vimg) + ((size_t)(b * NTILES + t)) * TILE_HW;
#pragma unroll
  for (int p = 0; p < 2; ++p) {
    const int ch = threadIdx.x + p * 256;  // key*16 + c
    const int key = ch >> 4, c = ch & 15;
    const float* src = src_base + ((size_t)(t * BK + key) * BB + b) * DD + c * 8;
    float4v f0 = *(const float4v*)src;
    float4v f1 = *(const float4v*)(src + 4);
    short8 s;
#pragma unroll
    for (int i = 0; i < 4; ++i) { s[i] = f2bf(f0[i]); s[4 + i] = f2bf(f1[i]); }
    *(short8*)&tile[key][c * 8] = s;
  }
  __syncthreads();
#pragma unroll
  for (int p = 0; p < 2; ++p) {
    const int idx = threadIdx.x + p * 256;
    const int j = idx >> 6, quad = (idx >> 4) & 3, mm = idx & 15;
    short8 s;
    if (blockIdx.z == 0) {
      const int ks = j >> 1, half = j & 1;
      s = *(const short8*)&tile[half * 16 + mm][(ks * 4 + quad) * 8];
    } else {
#pragma unroll
      for (int jj = 0; jj < 8; ++jj) s[jj] = tile[kappa(quad, jj)][j * 16 + mm];
    }
    *(short8*)(out + idx * 8) = s;
  }
}

// ---- attention: VERBATIM R10 (best measured: 8 waves = parity x qsub,
//      dbuf prefetch-1, single end-of-round __syncthreads, psum via
//      ones-MFMA, setprio around MFMA clusters). R11's T4 variant measured
//      -6 us vs this; reverted per pre-committed falsification branch. ----
__global__ __launch_bounds__(512) void attn_fwd(
    const float* __restrict__ qg, const short* __restrict__ kimg,
    const short* __restrict__ vimg, float* __restrict__ og) {
  // staging: 2 bufs x 2 parity groups x 8192 shorts (16 KB tile-pair) = 64 KB.
  // combine overlay (36,864 B) aliases the same region after the loop.
  __shared__ __align__(16) char smem_raw[65536];
  short* const sbuf = (short*)smem_raw;

  const int tid  = threadIdx.x;
  const int wave = tid >> 6;    // 0..7
  const int par  = wave >> 2;   // tile-stream parity of this wave's group
  const int qsub = wave & 3;    // q-row group: rows [qt*64 + qsub*16, +16)
  const int lane = tid & 63;
  const int m    = lane & 15;
  const int quad = lane >> 4;
  const int bid  = blockIdx.x;
  // XCD-local dispatch (verified R4-R10): xcd = bid&7 serves b in {2*xcd, 2*xcd+1}
  // -> 2 MB of images per XCD L2. Bijective over (b, qt).
  const int xcd = bid & 7;
  const int j   = bid >> 3;                 // 0..63
  const int qt  = (j < 32) ? j : 63 - j;    // 0..31
  const int b   = 2 * xcd + (j >> 5);
  const int qw  = qt * BQ + qsub * 16;
  const int qrow = qw + m;

  // Q fragments (B operand: lane&15 = q-row), 1/sqrt(D)*log2(e) folded
  const float cscale = 0.08838834764831845f * 1.4426950408889634f;
  short8 qfrag[4];
#pragma unroll
  for (int ks = 0; ks < 4; ++ks) {
    const float* qp = qg + ((size_t)qrow * BB + b) * DD + ks * 32 + quad * 8;
    float4v f0 = *(const float4v*)qp;
    float4v f1 = *(const float4v*)(qp + 4);
    short8 f;
#pragma unroll
    for (int i = 0; i < 4; ++i) { f[i] = f2bf(f0[i] * cscale); f[4 + i] = f2bf(f1[i] * cscale); }
    qfrag[ks] = f;
  }

  // ones-fragment (bf16 1.0 = 0x3F80) for the psum MFMA: P(16x32) . ones(32x16)
  // -> C[r][c] = rowsum(r) for every c; C layout puts rowsum(quad*4+rr) in
  // psacc[rr] of every lane in the quad-group (column-independent).
  short8 vones;
#pragma unroll
  for (int i = 0; i < 8; ++i) vones[i] = (short)0x3F80;

  float4v oacc[8];
#pragma unroll
  for (int i = 0; i < 8; ++i) oacc[i] = (float4v){0.f, 0.f, 0.f, 0.f};
  float4v psacc = {0.f, 0.f, 0.f, 0.f};

  // staging (verified chunk math): per tile-pair 16 chunks of 1KB
  // (K: LDS 0..7, V: 8..15); wave qsub owns LDS chunks [4*qsub, 4*qsub+4).
  // LDS dst wave-uniform (HW adds lane*16B); global src per-lane (+lane*8 shorts).
  const short* kbase = kimg + (size_t)b * NTILES * TILE_HW;
  const short* vbase = vimg + (size_t)b * NTILES * TILE_HW;
  const int cbase = qsub * 4;                       // 0,4,8,12
  const short* timg = (cbase < 8) ? kbase : vbase;  // qsub 0,1: K; 2,3: V
  const int coff = cbase & 7;                       // 0,4,0,4
  // double-buffered group regions
  short* const gbuf0 = sbuf + par * 8192;           // buf 0
  short* const gbuf1 = sbuf + 16384 + par * 8192;   // buf 1

  const int nround = qt + 1;  // tiles t = 2r+par, t <= 2qt+1 always valid

  // prologue: stage round-0 tile (t = par) into buf 0; make visible
  {
    const short* src = timg + (size_t)par * TILE_HW + coff * 512 + lane * 8;
#pragma unroll
    for (int c = 0; c < 4; ++c)
      __builtin_amdgcn_global_load_lds((glob_cv*)(src + c * 512),
                                       (lds_v*)&gbuf0[(cbase + c) * 512], 16, 0, 0);
  }
  __syncthreads();

  for (int r = 0; r < nround; ++r) {
    short* const cbuf = (r & 1) ? gbuf1 : gbuf0;  // compute from this buffer
    short* const nbuf = (r & 1) ? gbuf0 : gbuf1;  // stage next tile here

    if (r + 1 < nround) {  // block-uniform prefetch of round r+1's tile
      const int tn = 2 * (r + 1) + par;
      const short* src = timg + (size_t)tn * TILE_HW + coff * 512 + lane * 8;
#pragma unroll
      for (int c = 0; c < 4; ++c)
        __builtin_amdgcn_global_load_lds((glob_cv*)(src + c * 512),
                                         (lds_v*)&nbuf[(cbase + c) * 512], 16, 0, 0);
    }

    const int t = 2 * r + par;
    const short* kb = cbuf;
    const short* vb = cbuf + 8 * 512;

    // ---- S = K·Q^T (fragment-linear LDS reads, verified addressing) ----
    float4v s0 = {0.f, 0.f, 0.f, 0.f}, s1 = {0.f, 0.f, 0.f, 0.f};
    __builtin_amdgcn_s_setprio(1);
#pragma unroll
    for (int ks = 0; ks < 4; ++ks) {
      short8 kf0 = *(const short8*)(kb + (ks * 2 + 0) * 512 + lane * 8);
      short8 kf1 = *(const short8*)(kb + (ks * 2 + 1) * 512 + lane * 8);
      s0 = __builtin_amdgcn_mfma_f32_16x16x32_bf16(kf0, qfrag[ks], s0, 0, 0, 0);
      s1 = __builtin_amdgcn_mfma_f32_16x16x32_bf16(kf1, qfrag[ks], s1, 0, 0, 0);
    }
    __builtin_amdgcn_s_setprio(0);
    float sv[8];
#pragma unroll
    for (int rr = 0; rr < 4; ++rr) { sv[rr] = s0[rr]; sv[4 + rr] = s1[rr]; }

    const int kt0 = t * BK;
    if (kt0 + BK - 1 > qw) {  // wave-uniform: diagonal/above tiles only
#pragma unroll
      for (int jj = 0; jj < 8; ++jj)
        if (kt0 + kappa(quad, jj) > qrow) sv[jj] = -1e30f;
    }

    // ---- fixed-reference softmax: p = exp2(s); packed RTNE cvt (verified);
    //      fully-masked tiles yield p = 0 -> contribute exactly nothing.
    //      Row-sums accumulated by the ones-MFMA below, not VALU. ----
    union { short8 s8; uint32_t w[4]; } pf;
#pragma unroll
    for (int jp = 0; jp < 4; ++jp) {
      float p0 = exp2f(sv[2 * jp]);
      float p1 = exp2f(sv[2 * jp + 1]);
      uint32_t w;
      asm("v_cvt_pk_bf16_f32 %0, %1, %2" : "=v"(w) : "v"(p0), "v"(p1));
      pf.w[jp] = w;
    }
    const short8 pfrag = pf.s8;

    // ---- psum MFMA + PV (fragment-linear V reads) ----
    __builtin_amdgcn_s_setprio(1);
    psacc = __builtin_amdgcn_mfma_f32_16x16x32_bf16(pfrag, vones, psacc, 0, 0, 0);
#pragma unroll
    for (int nt = 0; nt < 8; ++nt) {
      short8 vf = *(const short8*)(vb + nt * 512 + lane * 8);
      oacc[nt] = __builtin_amdgcn_mfma_f32_16x16x32_bf16(pfrag, vf, oacc[nt], 0, 0, 0);
    }
    __builtin_amdgcn_s_setprio(0);

    __syncthreads();  // end-of-round: drains prefetch (aged a full compute
                      // phase) and orders LDS reads before next overwrite
  }

  // ---- combine parity-1 partials into parity-0 waves (verified R5/R7) ----
  __syncthreads();  // all loop LDS use done; overlay smem as float scratch
  float* const cw = (float*)smem_raw;  // 256*36*4 = 36,864 B <= 65,536 B
  if (par == 1) {
    float* p = cw + (size_t)(qsub * 64 + lane) * 36;
#pragma unroll
    for (int nt = 0; nt < 8; ++nt) *(float4v*)(p + nt * 4) = oacc[nt];
    *(float4v*)(p + 32) = psacc;
  }
  __syncthreads();
  if (par == 0) {
    const float* p = cw + (size_t)(qsub * 64 + lane) * 36;
#pragma unroll
    for (int nt = 0; nt < 8; ++nt) oacc[nt] += *(const float4v*)(p + nt * 4);
    psacc += *(const float4v*)(p + 32);

    // ---- epilogue: psacc[rr] = rowsum(qw + quad*4 + rr) directly (no shfl) ----
    float l4[4];
#pragma unroll
    for (int rr = 0; rr < 4; ++rr) l4[rr] = 1.0f / psacc[rr];
#pragma unroll
    for (int rr = 0; rr < 4; ++rr) {
      const int qgl = qw + quad * 4 + rr;
      float* op = og + ((size_t)qgl * BB + b) * DVV + m;
#pragma unroll
      for (int nt = 0; nt < 8; ++nt) op[nt * 16] = oacc[nt][rr] * l4[rr];
    }
  }
}

extern "C" void kernel_launch(void* const* d_in, const int* in_sizes, int n_in,
                              void* d_out, int out_size, void* d_ws, size_t ws_size,
                              hipStream_t stream) {
  const float* q = (const float*)d_in[0];
  const float* k = (const float*)d_in[1];
  const float* v = (const float*)d_in[2];
  float* out = (float*)d_out;
  short* kimg = (short*)d_ws;
  short* vimg = kimg + (size_t)BB * NTILES * TILE_HW;  // 8.39 MB each

  conv_kv<<<dim3(NTILES, BB, 2), 256, 0, stream>>>(k, v, kimg, vimg);
  attn_fwd<<<dim3(SS / BQ * BB), 512, 0, stream>>>(q, kimg, vimg, out);
}